// Round 4
// baseline (170.784 us; speedup 1.0000x reference)
//
#include <hip/hip_runtime.h>
#include <hip/hip_bf16.h>

#define DEV __device__ __forceinline__

typedef __attribute__((ext_vector_type(8))) short bf16x8;
typedef __attribute__((ext_vector_type(4))) float f32x4;

static constexpr int NR   = 16384;
static constexpr int DIN  = 512;
static constexpr int DHID = 2048;
static constexpr int DOUT = 512;
static constexpr int LR   = 64;          // 4 bands * rank 16
static constexpr int K1   = DIN + LR;    // 576
static constexpr int K2   = DHID + LR;   // 2112

DEV unsigned short f2bf(float f) {
  unsigned u = __float_as_uint(f);
  u += 0x7fffu + ((u >> 16) & 1u);
  return (unsigned short)(u >> 16);
}

// fast GELU: tanh-form, |err vs erf-form| < ~1.5e-3 (well under bf16 quantum of h)
DEV float fast_gelu(float v) {
  float x2 = v * v;
  float a  = -v * __builtin_fmaf(0.10294324f, x2, 2.30220817f);
  float t  = exp2f(a);
  return v * __builtin_amdgcn_rcpf(1.0f + t);
}

template<int N> DEV void wait_vm() {
  if constexpr (N == 0) asm volatile("s_waitcnt vmcnt(0)" ::: "memory");
  else if constexpr (N == 2) asm volatile("s_waitcnt vmcnt(2)" ::: "memory");
  else if constexpr (N == 4) asm volatile("s_waitcnt vmcnt(4)" ::: "memory");
  else if constexpr (N == 8) asm volatile("s_waitcnt vmcnt(8)" ::: "memory");
  else static_assert(N == 0, "unsupported vmcnt");
}

// ---- x fp32 -> bf16 into xaug[:, 0:512] (row stride K1) ----
__global__ __launch_bounds__(256) void cvt_x_kernel(const float* __restrict__ x,
                                                    unsigned short* __restrict__ xaug) {
  int i = blockIdx.x * 256 + threadIdx.x;   // one float4 per thread
  if (i >= NR * DIN / 4) return;
  int e = i * 4;
  int r = e >> 9, c = e & 511;
  float4 v = ((const float4*)x)[i];
  uint2 o;
  o.x = (unsigned)f2bf(v.x) | ((unsigned)f2bf(v.y) << 16);
  o.y = (unsigned)f2bf(v.z) | ((unsigned)f2bf(v.w) << 16);
  *(uint2*)(xaug + (size_t)r * K1 + c) = o;
}

// ---- generic transpose+convert: in fp32 [R][C] -> out bf16 [C][LDO] at col offset CO ----
template<int R, int C, int LDO, int CO>
__global__ __launch_bounds__(256) void tconv_kernel(const float* __restrict__ in,
                                                    unsigned short* __restrict__ out) {
  __shared__ float t[32][33];
  int bc = blockIdx.x * 32, br = blockIdx.y * 32;
  int tx = threadIdx.x & 31, ty = threadIdx.x >> 5;   // ty 0..7
  #pragma unroll
  for (int i = 0; i < 32; i += 8)
    t[ty + i][tx] = in[(size_t)(br + ty + i) * C + bc + tx];
  __syncthreads();
  #pragma unroll
  for (int i = 0; i < 32; i += 8)
    out[(size_t)(bc + ty + i) * LDO + CO + br + tx] = f2bf(t[tx][ty + i]);
}

// ---- LoRA A rearrange: A [4][D][16] fp32 -> AT [64][D] bf16 ----
__global__ __launch_bounds__(256) void rearrA_kernel(const float* __restrict__ A,
                                                     unsigned short* __restrict__ AT, int D) {
  int tid = blockIdx.x * 256 + threadIdx.x;
  if (tid >= 64 * D) return;
  int j = tid / D, i = tid - j * D;
  AT[tid] = f2bf(A[((size_t)(j >> 4) * D + i) * 16 + (j & 15)]);
}

// ---- main MFMA GEMM: BK=32, triple-buffered ring with counted vmcnt (T4),
//      source-swizzled LDS (T2 via m173 pattern), raw s_barrier.
// A: [M][lda] bf16 K-contig rows. B: [Ncols][ldb] bf16 K-contig rows (weight^T).
// EPI: 0 = gelu(acc+bias)->bf16 ; 1 = acc+bias->fp32 ; 2 = acc*2*bw[row][col>>4]->bf16
template<int BM, int BN, int WM, int WN, int K, int EPI>
__global__ __launch_bounds__(256) void gemm_kernel(
    const unsigned short* __restrict__ A, int lda,
    const unsigned short* __restrict__ B, int ldb,
    const float* __restrict__ bias, const float* __restrict__ bw,
    void* __restrict__ outp, int ldo, int ocol) {
  constexpr int WRM = WM / 16, WRN = WN / 16;
  constexpr int NWN = BN / WN;
  constexpr int NT  = K / 32;
  constexpr int NBUF = 3;
  constexpr int AISS = BM / 64;            // global_load_lds per thread for A per K-tile
  constexpr int BISS = BN / 64;
  constexpr int LOADS = AISS + BISS;       // loads/thread per staged tile
  static_assert((BM / WM) * (BN / WN) == 4, "4 waves");
  static_assert(NT >= NBUF, "need enough K tiles");
  __shared__ __align__(16) unsigned short lA[NBUF * BM * 32];
  __shared__ __align__(16) unsigned short lB[NBUF * BN * 32];

  const int tid  = threadIdx.x;
  const int wid  = tid >> 6, lane = tid & 63;
  const int wr   = wid / NWN, wc = wid % NWN;
  const int bm   = blockIdx.x * BM, bn = blockIdx.y * BN;
  // staging: 64 lanes = 16 rows x 4 chunks (16B each); src chunk XOR-swizzled by row&3
  const int srow = lane >> 2;
  const int scol = (((lane & 3) ^ ((lane >> 2) & 3)) * 8);
  // ds_read fragment chunk: logical (lane>>4) XOR row&3 (= lane&3 since row = ...16m + (lane&15))
  const int kch  = (((lane >> 4) ^ (lane & 3)) * 8);

  f32x4 acc[WRM][WRN] = {};

  auto stage = [&](int buf, int t) {
    #pragma unroll
    for (int i = 0; i < AISS; i++) {
      int row = i * 64 + wid * 16 + srow;
      __builtin_amdgcn_global_load_lds(
          (const __attribute__((address_space(1))) void*)
              (A + (size_t)(bm + row) * lda + t * 32 + scol),
          (__attribute__((address_space(3))) void*)(lA + buf * (BM * 32) + i * 2048 + wid * 512),
          16, 0, 0);
    }
    #pragma unroll
    for (int i = 0; i < BISS; i++) {
      int row = i * 64 + wid * 16 + srow;
      __builtin_amdgcn_global_load_lds(
          (const __attribute__((address_space(1))) void*)
              (B + (size_t)(bn + row) * ldb + t * 32 + scol),
          (__attribute__((address_space(3))) void*)(lB + buf * (BN * 32) + i * 2048 + wid * 512),
          16, 0, 0);
    }
  };

  auto compute = [&](int buf) {
    const unsigned short* pA = lA + buf * (BM * 32);
    const unsigned short* pB = lB + buf * (BN * 32);
    bf16x8 af[WRM], bfv[WRN];
    #pragma unroll
    for (int m = 0; m < WRM; m++)
      af[m] = *(const bf16x8*)(pA + (wr * WM + m * 16 + (lane & 15)) * 32 + kch);
    #pragma unroll
    for (int n = 0; n < WRN; n++)
      bfv[n] = *(const bf16x8*)(pB + (wc * WN + n * 16 + (lane & 15)) * 32 + kch);
    #pragma unroll
    for (int m = 0; m < WRM; m++)
      #pragma unroll
      for (int n = 0; n < WRN; n++)
        acc[m][n] = __builtin_amdgcn_mfma_f32_16x16x32_bf16(af[m], bfv[n], acc[m][n], 0, 0, 0);
  };

  // prologue: fill the ring (2-tile lookahead), wait only for tile 0
  stage(0, 0); stage(1, 1); stage(2, 2);
  wait_vm<2 * LOADS>();
  __builtin_amdgcn_s_barrier();

  int bt = 0;
  for (int t = 0; t < NT; ++t) {
    compute(bt);
    __builtin_amdgcn_s_barrier();          // all waves done reading buf bt (reads consumed by MFMA)
    if (t + 1 < NT) {
      if (t + NBUF < NT) stage(bt, t + NBUF);   // refill freed buf
      // loads newer than tile t+1's: tiles t+2 .. min(NT-1, t+NBUF)
      int newer = (t + NBUF < NT) ? (NBUF - 1) : (NT - 2 - t);
      if (newer >= 2)      wait_vm<2 * LOADS>();
      else if (newer == 1) wait_vm<LOADS>();
      else                 wait_vm<0>();
      __builtin_amdgcn_s_barrier();        // tile t+1 visible to all waves
      bt = (bt == NBUF - 1) ? 0 : bt + 1;
    }
  }

  // epilogue: C/D layout col=lane&15, row=(lane>>4)*4+reg (verified m89/m91)
  const int r0 = bm + wr * WM;
  const int c0 = bn + wc * WN;

  float biasv[WRN];
  if (EPI != 2) {
    #pragma unroll
    for (int n = 0; n < WRN; n++)
      biasv[n] = bias[c0 + n * 16 + (lane & 15)];
  }

  #pragma unroll
  for (int m = 0; m < WRM; m++) {
    #pragma unroll
    for (int n = 0; n < WRN; n++) {
      int col  = c0 + n * 16 + (lane & 15);
      int rowb = r0 + m * 16 + ((lane >> 4) << 2);
      #pragma unroll
      for (int r = 0; r < 4; r++) {
        float v = acc[m][n][r];
        int row = rowb + r;
        if (EPI == 0) {
          v = fast_gelu(v + biasv[n]);
          ((unsigned short*)outp)[(size_t)row * ldo + ocol + col] = f2bf(v);
        } else if (EPI == 1) {
          v += biasv[n];
          ((float*)outp)[(size_t)row * ldo + col] = v;
        } else {
          v *= 2.0f * bw[row * 4 + (col >> 4)];
          ((unsigned short*)outp)[(size_t)row * ldo + ocol + col] = f2bf(v);
        }
      }
    }
  }
}

extern "C" void kernel_launch(void* const* d_in, const int* in_sizes, int n_in,
                              void* d_out, int out_size, void* d_ws, size_t ws_size,
                              hipStream_t stream) {
  const float* x  = (const float*)d_in[0];
  const float* bw = (const float*)d_in[1];
  const float* W1 = (const float*)d_in[2];
  const float* b1 = (const float*)d_in[3];
  const float* W2 = (const float*)d_in[4];
  const float* b2 = (const float*)d_in[5];
  const float* A1 = (const float*)d_in[6];
  const float* B1 = (const float*)d_in[7];
  const float* A2 = (const float*)d_in[8];
  const float* B2 = (const float*)d_in[9];
  float* out = (float*)d_out;

  char* w = (char*)d_ws;
  unsigned short* xaug = (unsigned short*)w;  w += (size_t)NR * K1 * 2;       // 18.9 MB
  unsigned short* haug = (unsigned short*)w;  w += (size_t)NR * K2 * 2;       // 69.2 MB
  unsigned short* W1cT = (unsigned short*)w;  w += (size_t)DHID * K1 * 2;     // 2.36 MB
  unsigned short* W2cT = (unsigned short*)w;  w += (size_t)DOUT * K2 * 2;     // 2.16 MB
  unsigned short* A1T  = (unsigned short*)w;  w += (size_t)64 * DIN * 2;
  unsigned short* A2T  = (unsigned short*)w;  w += (size_t)64 * DHID * 2;

  // --- preprocessing ---
  cvt_x_kernel<<<NR * DIN / 4 / 256, 256, 0, stream>>>(x, xaug);
  tconv_kernel<512, 2048, K1, 0><<<dim3(64, 16), 256, 0, stream>>>(W1, W1cT);
  tconv_kernel<64, 2048, K1, 512><<<dim3(64, 2), 256, 0, stream>>>(B1, W1cT);
  tconv_kernel<2048, 512, K2, 0><<<dim3(16, 64), 256, 0, stream>>>(W2, W2cT);
  tconv_kernel<64, 512, K2, 2048><<<dim3(16, 2), 256, 0, stream>>>(B2, W2cT);
  rearrA_kernel<<<128, 256, 0, stream>>>(A1, A1T, 512);
  rearrA_kernel<<<512, 256, 0, stream>>>(A2, A2T, 2048);

  // --- u1 = 2*bw ⊙ (x @ A1cat)  -> xaug[:, 512:576] ---
  gemm_kernel<64, 64, 32, 32, 512, 2><<<dim3(NR / 64, 1), 256, 0, stream>>>(
      xaug, K1, A1T, DIN, nullptr, bw, xaug, K1, 512);
  // --- h = gelu(xaug @ [W1;B1cat] + b1) -> haug[:, 0:2048] ---
  gemm_kernel<128, 128, 64, 64, K1, 0><<<dim3(NR / 128, DHID / 128), 256, 0, stream>>>(
      xaug, K1, W1cT, K1, b1, nullptr, haug, K2, 0);
  // --- u2 = 2*bw ⊙ (h @ A2cat) -> haug[:, 2048:2112] ---
  gemm_kernel<64, 64, 32, 32, 2048, 2><<<dim3(NR / 64, 1), 256, 0, stream>>>(
      haug, K2, A2T, DHID, nullptr, bw, haug, K2, 2048);
  // --- out = haug @ [W2;B2cat] + b2 (fp32) ---
  gemm_kernel<128, 128, 64, 64, K2, 1><<<dim3(NR / 128, DOUT / 128), 256, 0, stream>>>(
      haug, K2, W2cT, K2, b2, nullptr, out, DOUT, 0);
}

// Round 5
// 170.275 us; speedup vs baseline: 1.0030x; 1.0030x over previous
//
#include <hip/hip_runtime.h>
#include <hip/hip_bf16.h>

#define DEV __device__ __forceinline__
#define AS1 __attribute__((address_space(1)))
#define AS3 __attribute__((address_space(3)))

typedef __attribute__((ext_vector_type(8))) short bf16x8;
typedef __attribute__((ext_vector_type(4))) float f32x4;

static constexpr int NR   = 16384;
static constexpr int DIN  = 512;
static constexpr int DHID = 2048;
static constexpr int DOUT = 512;
static constexpr int LR   = 64;          // 4 bands * rank 16
static constexpr int K1   = DIN + LR;    // 576
static constexpr int K2   = DHID + LR;   // 2112

DEV unsigned short f2bf(float f) {
  unsigned u = __float_as_uint(f);
  u += 0x7fffu + ((u >> 16) & 1u);
  return (unsigned short)(u >> 16);
}

// fast GELU: tanh-form, |err vs erf-form| < ~1.5e-3 (well under bf16 quantum of h)
DEV float fast_gelu(float v) {
  float x2 = v * v;
  float a  = -v * __builtin_fmaf(0.10294324f, x2, 2.30220817f);
  float t  = exp2f(a);
  return v * __builtin_amdgcn_rcpf(1.0f + t);
}

template<int N> DEV void wvm() {
  asm volatile("s_waitcnt vmcnt(%0)" :: "i"(N) : "memory");
}

// ---- x fp32 -> bf16 into xaug[:, 0:512] (row stride K1) ----
__global__ __launch_bounds__(256) void cvt_x_kernel(const float* __restrict__ x,
                                                    unsigned short* __restrict__ xaug) {
  int i = blockIdx.x * 256 + threadIdx.x;   // one float4 per thread
  if (i >= NR * DIN / 4) return;
  int e = i * 4;
  int r = e >> 9, c = e & 511;
  float4 v = ((const float4*)x)[i];
  uint2 o;
  o.x = (unsigned)f2bf(v.x) | ((unsigned)f2bf(v.y) << 16);
  o.y = (unsigned)f2bf(v.z) | ((unsigned)f2bf(v.w) << 16);
  *(uint2*)(xaug + (size_t)r * K1 + c) = o;
}

// ---- generic transpose+convert: in fp32 [R][C] -> out bf16 [C][LDO] at col offset CO ----
template<int R, int C, int LDO, int CO>
__global__ __launch_bounds__(256) void tconv_kernel(const float* __restrict__ in,
                                                    unsigned short* __restrict__ out) {
  __shared__ float t[32][33];
  int bc = blockIdx.x * 32, br = blockIdx.y * 32;
  int tx = threadIdx.x & 31, ty = threadIdx.x >> 5;   // ty 0..7
  #pragma unroll
  for (int i = 0; i < 32; i += 8)
    t[ty + i][tx] = in[(size_t)(br + ty + i) * C + bc + tx];
  __syncthreads();
  #pragma unroll
  for (int i = 0; i < 32; i += 8)
    out[(size_t)(bc + ty + i) * LDO + CO + br + tx] = f2bf(t[tx][ty + i]);
}

// ---- LoRA A rearrange: A [4][D][16] fp32 -> AT [64][D] bf16 ----
__global__ __launch_bounds__(256) void rearrA_kernel(const float* __restrict__ A,
                                                     unsigned short* __restrict__ AT, int D) {
  int tid = blockIdx.x * 256 + threadIdx.x;
  if (tid >= 64 * D) return;
  int j = tid / D, i = tid - j * D;
  AT[tid] = f2bf(A[((size_t)(j >> 4) * D + i) * 16 + (j & 15)]);
}

// ==================== 8-phase 256-wide MFMA GEMM (T2+T3+T4+T5) ====================
// A: [M][lda] bf16 K-contig. B: [256-col panel][ldb] bf16 K-contig (weight^T).
// BN=256, BK=64, 8 waves (2Mx4N), 512 threads. Phase = C-quadrant (qm,qn) 128xBN/2 x K64.
// Stage ledger (per tile i): ph0:hA1(i+1) ph1:hB1(i+1) ph2:hA0(i+2) ph3:hB0(i+2).
// End-of-phase waits (steady): {2AL+BL, 2AL+3BL, -, 2AL+2BL}; tails exact-drain.
// EPI: 0 = gelu(acc+bias)->bf16 out ; 1 = acc+bias->fp32 out
template<int BM, int K, int EPI>
__global__ __launch_bounds__(512, 2) void gemm8_kernel(
    const unsigned short* __restrict__ A, int lda,
    const unsigned short* __restrict__ B, int ldb,
    const float* __restrict__ bias,
    void* __restrict__ outp, int ldo, int ocol) {
  constexpr int NT = K / 64;
  constexpr int AL = BM / 128;           // gload_lds calls/thread per A half (2|1)
  constexpr int BL = 2;                  // per B half
  constexpr int HA = (BM / 2) * 64;      // elems per A half-slot
  constexpr int HB = 128 * 64;           // elems per B half-slot
  constexpr int MQ = (BM / 4) / 16;      // m-frags per wave per phase (4|2)
  constexpr int NQ = 2;                  // n-frags per wave per phase
  static_assert(NT >= 3 && K % 64 == 0, "K tiles");
  __shared__ __align__(16) unsigned short lA[4 * HA];   // [buf][half]
  __shared__ __align__(16) unsigned short lB[4 * HB];

  const int tid  = threadIdx.x;
  const int w    = tid >> 6, lane = tid & 63;
  const int wr   = w >> 2, wc = w & 3;          // 2M x 4N
  const int bm   = blockIdx.x * BM, bn = blockIdx.y * 256;

  f32x4 acc[2][2][MQ][NQ] = {};

  auto stageA = [&](int buf, int half, int t) {
    #pragma unroll
    for (int i = 0; i < AL; ++i) {
      int row = w * (AL * 8) + i * 8 + (lane >> 3);
      __builtin_amdgcn_global_load_lds(
          (const AS1 void*)(A + (size_t)(bm + half * (BM / 2) + row) * lda
                              + (size_t)t * 64 + (((lane & 7) ^ (row & 7)) * 8)),
          (AS3 void*)(lA + (buf * 2 + half) * HA + (w * AL + i) * 512),
          16, 0, 0);
    }
  };
  auto stageB = [&](int buf, int half, int t) {
    #pragma unroll
    for (int i = 0; i < BL; ++i) {
      int row = w * 16 + i * 8 + (lane >> 3);
      __builtin_amdgcn_global_load_lds(
          (const AS1 void*)(B + (size_t)(bn + half * 128 + row) * ldb
                              + (size_t)t * 64 + (((lane & 7) ^ (row & 7)) * 8)),
          (AS3 void*)(lB + (buf * 2 + half) * HB + (w * BL + i) * 512),
          16, 0, 0);
    }
  };

#define RD_FRAGS(buf, qm, qn)                                                    \
  {                                                                              \
    const unsigned short* sA = lA + ((buf) * 2 + (qm)) * HA;                     \
    const unsigned short* sB = lB + ((buf) * 2 + (qn)) * HB;                     \
    _Pragma("unroll")                                                            \
    for (int m = 0; m < MQ; ++m) {                                               \
      int row = wr * (BM / 4) + m * 16 + (lane & 15);                            \
      _Pragma("unroll")                                                          \
      for (int kk = 0; kk < 2; ++kk)                                             \
        af[m][kk] = *(const bf16x8*)(sA + row * 64 +                             \
                       (((kk * 4 + (lane >> 4)) ^ (lane & 7)) * 8));             \
    }                                                                            \
    _Pragma("unroll")                                                            \
    for (int n = 0; n < NQ; ++n) {                                               \
      int row = wc * 32 + n * 16 + (lane & 15);                                  \
      _Pragma("unroll")                                                          \
      for (int kk = 0; kk < 2; ++kk)                                             \
        bfv[n][kk] = *(const bf16x8*)(sB + row * 64 +                            \
                       (((kk * 4 + (lane >> 4)) ^ (lane & 7)) * 8));             \
    }                                                                            \
  }

#define MFMA_Q(qm, qn)                                                           \
  __builtin_amdgcn_s_setprio(1);                                                 \
  _Pragma("unroll")                                                              \
  for (int m = 0; m < MQ; ++m)                                                   \
    _Pragma("unroll")                                                            \
    for (int n = 0; n < NQ; ++n) {                                               \
      acc[qm][qn][m][n] = __builtin_amdgcn_mfma_f32_16x16x32_bf16(               \
          af[m][0], bfv[n][0], acc[qm][qn][m][n], 0, 0, 0);                      \
      acc[qm][qn][m][n] = __builtin_amdgcn_mfma_f32_16x16x32_bf16(               \
          af[m][1], bfv[n][1], acc[qm][qn][m][n], 0, 0, 0);                      \
    }                                                                            \
  __builtin_amdgcn_s_setprio(0);

  // prologue: tile0 fully + hA0/hB0 of tile1; wait tile0's first halves landed
  stageA(0, 0, 0); stageB(0, 0, 0); stageA(0, 1, 0); stageB(0, 1, 0);
  stageA(1, 0, 1); stageB(1, 0, 1);
  wvm<2 * AL + 2 * BL>();
  __builtin_amdgcn_s_barrier();

  for (int i = 0; i < NT; ++i) {
    const int buf = i & 1, nb = buf ^ 1;
    bf16x8 af[MQ][2], bfv[NQ][2];
    // ---- phase 0: quadrant (0,0)
    RD_FRAGS(buf, 0, 0);
    if (i + 1 < NT) stageA(nb, 1, i + 1);
    __builtin_amdgcn_s_barrier();
    MFMA_Q(0, 0);
    if (i + 1 < NT) wvm<2 * AL + BL>(); else wvm<0>();
    __builtin_amdgcn_s_barrier();
    // ---- phase 1: quadrant (0,1)
    RD_FRAGS(buf, 0, 1);
    if (i + 1 < NT) stageB(nb, 1, i + 1);
    __builtin_amdgcn_s_barrier();
    MFMA_Q(0, 1);
    if (i + 1 < NT) wvm<2 * AL + 3 * BL>();
    __builtin_amdgcn_s_barrier();
    // ---- phase 2: quadrant (1,0)
    RD_FRAGS(buf, 1, 0);
    if (i + 2 < NT) stageA(buf, 0, i + 2);
    __builtin_amdgcn_s_barrier();
    MFMA_Q(1, 0);
    __builtin_amdgcn_s_barrier();
    // ---- phase 3: quadrant (1,1)
    RD_FRAGS(buf, 1, 1);
    if (i + 2 < NT) stageB(buf, 0, i + 2);
    __builtin_amdgcn_s_barrier();
    MFMA_Q(1, 1);
    if (i + 2 < NT) wvm<2 * AL + 2 * BL>();
    else if (i + 1 < NT) wvm<AL + BL>();
    __builtin_amdgcn_s_barrier();
  }
#undef RD_FRAGS
#undef MFMA_Q

  // epilogue: C/D layout col=lane&15, row=(lane>>4)*4+reg
  const int r0 = bm + wr * (BM / 4);
  const int c0 = bn + wc * 32;
  float biasv[2][NQ];
  #pragma unroll
  for (int qn = 0; qn < 2; ++qn)
    #pragma unroll
    for (int n = 0; n < NQ; ++n)
      biasv[qn][n] = bias[c0 + qn * 128 + n * 16 + (lane & 15)];

  #pragma unroll
  for (int qm = 0; qm < 2; ++qm)
    #pragma unroll
    for (int qn = 0; qn < 2; ++qn)
      #pragma unroll
      for (int m = 0; m < MQ; ++m)
        #pragma unroll
        for (int n = 0; n < NQ; ++n) {
          int col  = c0 + qn * 128 + n * 16 + (lane & 15);
          int rowb = r0 + qm * (BM / 2) + m * 16 + ((lane >> 4) << 2);
          #pragma unroll
          for (int r = 0; r < 4; ++r) {
            float v = acc[qm][qn][m][n][r];
            int row = rowb + r;
            if (EPI == 0) {
              v = fast_gelu(v + biasv[qn][n]);
              ((unsigned short*)outp)[(size_t)row * ldo + ocol + col] = f2bf(v);
            } else {
              v += biasv[qn][n];
              ((float*)outp)[(size_t)row * ldo + col] = v;
            }
          }
        }
}

// ==================== small 2-phase GEMM for the LoRA u-projections ====================
// (validated R4 structure: BK=32 triple-buffer ring, counted vmcnt)
// EPI2: acc*2*bw[row][col>>4] -> bf16 out at col offset
template<int BM, int BN, int WM, int WN, int K>
__global__ __launch_bounds__(256) void gemmu_kernel(
    const unsigned short* __restrict__ A, int lda,
    const unsigned short* __restrict__ B, int ldb,
    const float* __restrict__ bw,
    unsigned short* __restrict__ outp, int ldo, int ocol) {
  constexpr int WRM = WM / 16, WRN = WN / 16;
  constexpr int NWN = BN / WN;
  constexpr int NT  = K / 32;
  constexpr int NBUF = 3;
  constexpr int AISS = BM / 64;
  constexpr int BISS = BN / 64;
  constexpr int LOADS = AISS + BISS;
  static_assert((BM / WM) * (BN / WN) == 4, "4 waves");
  __shared__ __align__(16) unsigned short lA[NBUF * BM * 32];
  __shared__ __align__(16) unsigned short lB[NBUF * BN * 32];

  const int tid  = threadIdx.x;
  const int wid  = tid >> 6, lane = tid & 63;
  const int wr   = wid / NWN, wc = wid % NWN;
  const int bm   = blockIdx.x * BM, bn = blockIdx.y * BN;
  const int srow = lane >> 2;
  const int scol = (((lane & 3) ^ ((lane >> 2) & 3)) * 8);
  const int kch  = (((lane >> 4) ^ (lane & 3)) * 8);

  f32x4 acc[WRM][WRN] = {};

  auto stage = [&](int buf, int t) {
    #pragma unroll
    for (int i = 0; i < AISS; i++) {
      int row = i * 64 + wid * 16 + srow;
      __builtin_amdgcn_global_load_lds(
          (const AS1 void*)(A + (size_t)(bm + row) * lda + t * 32 + scol),
          (AS3 void*)(lA + buf * (BM * 32) + i * 2048 + wid * 512), 16, 0, 0);
    }
    #pragma unroll
    for (int i = 0; i < BISS; i++) {
      int row = i * 64 + wid * 16 + srow;
      __builtin_amdgcn_global_load_lds(
          (const AS1 void*)(B + (size_t)(bn + row) * ldb + t * 32 + scol),
          (AS3 void*)(lB + buf * (BN * 32) + i * 2048 + wid * 512), 16, 0, 0);
    }
  };
  auto compute = [&](int buf) {
    const unsigned short* pA = lA + buf * (BM * 32);
    const unsigned short* pB = lB + buf * (BN * 32);
    bf16x8 af[WRM], bfv[WRN];
    #pragma unroll
    for (int m = 0; m < WRM; m++)
      af[m] = *(const bf16x8*)(pA + (wr * WM + m * 16 + (lane & 15)) * 32 + kch);
    #pragma unroll
    for (int n = 0; n < WRN; n++)
      bfv[n] = *(const bf16x8*)(pB + (wc * WN + n * 16 + (lane & 15)) * 32 + kch);
    #pragma unroll
    for (int m = 0; m < WRM; m++)
      #pragma unroll
      for (int n = 0; n < WRN; n++)
        acc[m][n] = __builtin_amdgcn_mfma_f32_16x16x32_bf16(af[m], bfv[n], acc[m][n], 0, 0, 0);
  };

  stage(0, 0); stage(1, 1); stage(2, 2);
  wvm<2 * LOADS>();
  __builtin_amdgcn_s_barrier();

  int bt = 0;
  for (int t = 0; t < NT; ++t) {
    compute(bt);
    __builtin_amdgcn_s_barrier();
    if (t + 1 < NT) {
      if (t + NBUF < NT) stage(bt, t + NBUF);
      int newer = (t + NBUF < NT) ? (NBUF - 1) : (NT - 2 - t);
      if (newer >= 2)      wvm<2 * LOADS>();
      else if (newer == 1) wvm<LOADS>();
      else                 wvm<0>();
      __builtin_amdgcn_s_barrier();
      bt = (bt == NBUF - 1) ? 0 : bt + 1;
    }
  }

  const int r0 = bm + wr * WM;
  const int c0 = bn + wc * WN;
  #pragma unroll
  for (int m = 0; m < WRM; m++)
    #pragma unroll
    for (int n = 0; n < WRN; n++) {
      int col  = c0 + n * 16 + (lane & 15);
      int rowb = r0 + m * 16 + ((lane >> 4) << 2);
      #pragma unroll
      for (int r = 0; r < 4; r++) {
        float v = acc[m][n][r] * 2.0f * bw[(rowb + r) * 4 + (col >> 4)];
        outp[(size_t)(rowb + r) * ldo + ocol + col] = f2bf(v);
      }
    }
}

extern "C" void kernel_launch(void* const* d_in, const int* in_sizes, int n_in,
                              void* d_out, int out_size, void* d_ws, size_t ws_size,
                              hipStream_t stream) {
  const float* x  = (const float*)d_in[0];
  const float* bw = (const float*)d_in[1];
  const float* W1 = (const float*)d_in[2];
  const float* b1 = (const float*)d_in[3];
  const float* W2 = (const float*)d_in[4];
  const float* b2 = (const float*)d_in[5];
  const float* A1 = (const float*)d_in[6];
  const float* B1 = (const float*)d_in[7];
  const float* A2 = (const float*)d_in[8];
  const float* B2 = (const float*)d_in[9];
  float* out = (float*)d_out;

  char* w = (char*)d_ws;
  unsigned short* xaug = (unsigned short*)w;  w += (size_t)NR * K1 * 2;       // 18.9 MB
  unsigned short* haug = (unsigned short*)w;  w += (size_t)NR * K2 * 2;       // 69.2 MB
  unsigned short* W1cT = (unsigned short*)w;  w += (size_t)DHID * K1 * 2;     // 2.36 MB
  unsigned short* W2cT = (unsigned short*)w;  w += (size_t)DOUT * K2 * 2;     // 2.16 MB
  unsigned short* A1T  = (unsigned short*)w;  w += (size_t)64 * DIN * 2;
  unsigned short* A2T  = (unsigned short*)w;  w += (size_t)64 * DHID * 2;

  // --- preprocessing ---
  cvt_x_kernel<<<NR * DIN / 4 / 256, 256, 0, stream>>>(x, xaug);
  tconv_kernel<512, 2048, K1, 0><<<dim3(64, 16), 256, 0, stream>>>(W1, W1cT);
  tconv_kernel<64, 2048, K1, 512><<<dim3(64, 2), 256, 0, stream>>>(B1, W1cT);
  tconv_kernel<2048, 512, K2, 0><<<dim3(16, 64), 256, 0, stream>>>(W2, W2cT);
  tconv_kernel<64, 512, K2, 2048><<<dim3(16, 2), 256, 0, stream>>>(B2, W2cT);
  rearrA_kernel<<<128, 256, 0, stream>>>(A1, A1T, 512);
  rearrA_kernel<<<512, 256, 0, stream>>>(A2, A2T, 2048);

  // --- u1 = 2*bw ⊙ (x @ A1cat)  -> xaug[:, 512:576] ---
  gemmu_kernel<64, 64, 32, 32, 512><<<dim3(NR / 64, 1), 256, 0, stream>>>(
      xaug, K1, A1T, DIN, bw, xaug, K1, 512);
  // --- h = gelu(xaug @ [W1;B1cat] + b1) -> haug[:, 0:2048] ---
  gemm8_kernel<256, K1, 0><<<dim3(NR / 256, DHID / 256), 512, 0, stream>>>(
      xaug, K1, W1cT, K1, b1, haug, K2, 0);
  // --- u2 = 2*bw ⊙ (h @ A2cat) -> haug[:, 2048:2112] ---
  gemmu_kernel<64, 64, 32, 32, 2048><<<dim3(NR / 64, 1), 256, 0, stream>>>(
      haug, K2, A2T, DHID, bw, haug, K2, 2048);
  // --- out = haug @ [W2;B2cat] + b2 (fp32) ---
  gemm8_kernel<128, K2, 1><<<dim3(NR / 128, DOUT / 256), 512, 0, stream>>>(
      haug, K2, W2cT, K2, b2, out, DOUT, 0);
}

// Round 6
// 156.633 us; speedup vs baseline: 1.0903x; 1.0871x over previous
//
#include <hip/hip_runtime.h>
#include <hip/hip_bf16.h>

#define DEV __device__ __forceinline__
#define AS1 __attribute__((address_space(1)))
#define AS3 __attribute__((address_space(3)))

typedef __attribute__((ext_vector_type(8))) short bf16x8;
typedef __attribute__((ext_vector_type(4))) float f32x4;

static constexpr int NR   = 16384;
static constexpr int DIN  = 512;
static constexpr int DHID = 2048;
static constexpr int DOUT = 512;
static constexpr int LR   = 64;          // 4 bands * rank 16
static constexpr int K1   = DIN + LR;    // 576
static constexpr int K2   = DHID + LR;   // 2112

DEV unsigned short f2bf(float f) {
  unsigned u = __float_as_uint(f);
  u += 0x7fffu + ((u >> 16) & 1u);
  return (unsigned short)(u >> 16);
}

// fast GELU: tanh-form, |err vs erf-form| < ~1.5e-3 (well under bf16 quantum of h)
DEV float fast_gelu(float v) {
  float x2 = v * v;
  float a  = -v * __builtin_fmaf(0.10294324f, x2, 2.30220817f);
  float t  = exp2f(a);
  return v * __builtin_amdgcn_rcpf(1.0f + t);
}

template<int N> DEV void wvm() {
  asm volatile("s_waitcnt vmcnt(%0)" :: "i"(N) : "memory");
}

// ---- x fp32 -> bf16 into xaug[:, 0:512] (row stride K1) ----
__global__ __launch_bounds__(256) void cvt_x_kernel(const float* __restrict__ x,
                                                    unsigned short* __restrict__ xaug) {
  int i = blockIdx.x * 256 + threadIdx.x;   // one float4 per thread
  if (i >= NR * DIN / 4) return;
  int e = i * 4;
  int r = e >> 9, c = e & 511;
  float4 v = ((const float4*)x)[i];
  uint2 o;
  o.x = (unsigned)f2bf(v.x) | ((unsigned)f2bf(v.y) << 16);
  o.y = (unsigned)f2bf(v.z) | ((unsigned)f2bf(v.w) << 16);
  *(uint2*)(xaug + (size_t)r * K1 + c) = o;
}

// ---- generic transpose+convert: in fp32 [R][C] -> out bf16 [C][LDO] at col offset CO ----
template<int R, int C, int LDO, int CO>
__global__ __launch_bounds__(256) void tconv_kernel(const float* __restrict__ in,
                                                    unsigned short* __restrict__ out) {
  __shared__ float t[32][33];
  int bc = blockIdx.x * 32, br = blockIdx.y * 32;
  int tx = threadIdx.x & 31, ty = threadIdx.x >> 5;   // ty 0..7
  #pragma unroll
  for (int i = 0; i < 32; i += 8)
    t[ty + i][tx] = in[(size_t)(br + ty + i) * C + bc + tx];
  __syncthreads();
  #pragma unroll
  for (int i = 0; i < 32; i += 8)
    out[(size_t)(bc + ty + i) * LDO + CO + br + tx] = f2bf(t[tx][ty + i]);
}

// ---- LoRA A rearrange: A [4][D][16] fp32 -> AT [64][D] bf16 ----
__global__ __launch_bounds__(256) void rearrA_kernel(const float* __restrict__ A,
                                                     unsigned short* __restrict__ AT, int D) {
  int tid = blockIdx.x * 256 + threadIdx.x;
  if (tid >= 64 * D) return;
  int j = tid / D, i = tid - j * D;
  AT[tid] = f2bf(A[((size_t)(j >> 4) * D + i) * 16 + (j & 15)]);
}

// ==================== 8-phase 256-wide MFMA GEMM (T2+T3+T4+T5), v2 ====================
// Wave tile: (BM/2) x 64 split across halves: mh0 in A-half0, mh1 in A-half1,
// nh0 in B-half0, nh1 in B-half1. Phase order (mh,nh): (0,0),(0,1),(1,1),(1,0).
// af loaded ph0/ph2 (reused next phase); bfv fully resident (loaded ph0/ph1).
// Stage ledger (tile i -> tile i+1): ph0:A0, ph1:B0, ph2:B1, ph3:A1.
// Needs in tile i+1: A0,B0 @ph0; B1 @ph1; A1 @ph2  => all waits cover >=2 phases.
// Waits (steady): end-ph0 vmcnt(2AL) [B1(i) landed], end-ph1 vmcnt(AL+BL) [A1(i)],
// end-ph2 none, end-ph3 vmcnt(AL+BL) [A0,B0(i+1)]. Tails exact-drain.
// EPI: 0 = gelu(acc+bias)->bf16 out ; 1 = acc+bias->fp32 out
template<int BM, int K, int EPI>
__global__ __launch_bounds__(512, 2) void gemm8_kernel(
    const unsigned short* __restrict__ A, int lda,
    const unsigned short* __restrict__ B, int ldb,
    const float* __restrict__ bias,
    void* __restrict__ outp, int ldo, int ocol) {
  constexpr int NT = K / 64;
  constexpr int AL = BM / 128;           // gload_lds/thread per A half (2|1)
  constexpr int BL = 2;                  // per B half (128 rows)
  constexpr int HA = (BM / 2) * 64;      // elems per A half-slot
  constexpr int HB = 128 * 64;
  constexpr int MQ = BM / 64;            // m-frags per phase per wave (4|2)
  static_assert(NT >= 2 && K % 64 == 0, "K tiles");
  __shared__ __align__(16) unsigned short lA[4 * HA];   // [buf][half]
  __shared__ __align__(16) unsigned short lB[4 * HB];

  const int tid  = threadIdx.x;
  const int w    = tid >> 6, lane = tid & 63;
  const int wr   = w >> 2, wc = w & 3;          // 2M x 4N
  const int bm   = blockIdx.x * BM, bn = blockIdx.y * 256;
  const int l15  = lane & 15;
  const int kc0  = ((lane >> 4) ^ (lane & 7)) * 8;        // kk=0 chunk (swizzled)
  const int kc1  = (((lane >> 4) + 4) ^ (lane & 7)) * 8;  // kk=1 chunk

  f32x4 acc[2][2][MQ][2] = {};   // [mh][nh][m][n]
  bf16x8 af[MQ][2];              // current mh's A frags
  bf16x8 bfv[2][2][2];           // [nh][n][kk], fully resident

  auto stageA = [&](int buf, int half, int t) {
    #pragma unroll
    for (int i = 0; i < AL; ++i) {
      int row = w * (AL * 8) + i * 8 + (lane >> 3);
      __builtin_amdgcn_global_load_lds(
          (const AS1 void*)(A + (size_t)(bm + half * (BM / 2) + row) * lda
                              + (size_t)t * 64 + (((lane & 7) ^ (row & 7)) * 8)),
          (AS3 void*)(lA + (buf * 2 + half) * HA + (w * AL + i) * 512),
          16, 0, 0);
    }
  };
  auto stageB = [&](int buf, int half, int t) {
    #pragma unroll
    for (int i = 0; i < BL; ++i) {
      int row = w * 16 + i * 8 + (lane >> 3);
      __builtin_amdgcn_global_load_lds(
          (const AS1 void*)(B + (size_t)(bn + half * 128 + row) * ldb
                              + (size_t)t * 64 + (((lane & 7) ^ (row & 7)) * 8)),
          (AS3 void*)(lB + (buf * 2 + half) * HB + (w * BL + i) * 512),
          16, 0, 0);
    }
  };
  auto ldA = [&](int buf, int mh) {
    const unsigned short* sA = lA + (buf * 2 + mh) * HA;
    #pragma unroll
    for (int m = 0; m < MQ; ++m) {
      int ro = (wr * (BM / 4) + m * 16 + l15) * 64;
      af[m][0] = *(const bf16x8*)(sA + ro + kc0);
      af[m][1] = *(const bf16x8*)(sA + ro + kc1);
    }
  };
  auto ldB = [&](int buf, int nh) {
    const unsigned short* sB = lB + (buf * 2 + nh) * HB;
    #pragma unroll
    for (int n = 0; n < 2; ++n) {
      int ro = (wc * 32 + n * 16 + l15) * 64;
      bfv[nh][n][0] = *(const bf16x8*)(sB + ro + kc0);
      bfv[nh][n][1] = *(const bf16x8*)(sB + ro + kc1);
    }
  };

#define MFMA_Q(mh, nh)                                                           \
  __builtin_amdgcn_s_setprio(1);                                                 \
  _Pragma("unroll")                                                              \
  for (int m = 0; m < MQ; ++m)                                                   \
    _Pragma("unroll")                                                            \
    for (int n = 0; n < 2; ++n) {                                                \
      acc[mh][nh][m][n] = __builtin_amdgcn_mfma_f32_16x16x32_bf16(               \
          af[m][0], bfv[nh][n][0], acc[mh][nh][m][n], 0, 0, 0);                  \
      acc[mh][nh][m][n] = __builtin_amdgcn_mfma_f32_16x16x32_bf16(               \
          af[m][1], bfv[nh][n][1], acc[mh][nh][m][n], 0, 0, 0);                  \
    }                                                                            \
  __builtin_amdgcn_s_setprio(0);

  // prologue: tile0, order A0,B0,B1,A1; wait until A0,B0 landed
  stageA(0, 0, 0); stageB(0, 0, 0); stageB(0, 1, 0); stageA(0, 1, 0);
  wvm<AL + BL>();
  __builtin_amdgcn_s_barrier();

  for (int i = 0; i < NT; ++i) {
    const int buf = i & 1, nb = buf ^ 1;
    const bool more = (i + 1 < NT);
    // ---- phase 0: (mh0, nh0)
    ldA(buf, 0);
    ldB(buf, 0);
    if (more) stageA(nb, 0, i + 1);
    __builtin_amdgcn_s_barrier();
    MFMA_Q(0, 0);
    if (more) wvm<2 * AL>(); else wvm<AL>();       // B1(i) landed
    __builtin_amdgcn_s_barrier();
    // ---- phase 1: (mh0, nh1)
    ldB(buf, 1);
    if (more) stageB(nb, 0, i + 1);
    __builtin_amdgcn_s_barrier();
    MFMA_Q(0, 1);
    if (more) wvm<AL + BL>(); else wvm<0>();       // A1(i) landed
    __builtin_amdgcn_s_barrier();
    // ---- phase 2: (mh1, nh1)
    ldA(buf, 1);
    if (more) stageB(nb, 1, i + 1);
    __builtin_amdgcn_s_barrier();
    MFMA_Q(1, 1);
    __builtin_amdgcn_s_barrier();
    // ---- phase 3: (mh1, nh0)  (no ds loads; af/bfv resident)
    if (more) stageA(nb, 1, i + 1);
    __builtin_amdgcn_s_barrier();
    MFMA_Q(1, 0);
    if (more) wvm<AL + BL>();                      // A0(i+1),B0(i+1) landed
    __builtin_amdgcn_s_barrier();
  }
#undef MFMA_Q

  // epilogue: C/D layout col=lane&15, row=(lane>>4)*4+reg
  float biasv[2][2];
  #pragma unroll
  for (int nh = 0; nh < 2; ++nh)
    #pragma unroll
    for (int n = 0; n < 2; ++n)
      biasv[nh][n] = bias[bn + nh * 128 + wc * 32 + n * 16 + l15];

  #pragma unroll
  for (int mh = 0; mh < 2; ++mh)
    #pragma unroll
    for (int nh = 0; nh < 2; ++nh)
      #pragma unroll
      for (int m = 0; m < MQ; ++m)
        #pragma unroll
        for (int n = 0; n < 2; ++n) {
          int col  = bn + nh * 128 + wc * 32 + n * 16 + l15;
          int rowb = bm + mh * (BM / 2) + wr * (BM / 4) + m * 16 + ((lane >> 4) << 2);
          #pragma unroll
          for (int r = 0; r < 4; ++r) {
            float v = acc[mh][nh][m][n][r];
            int row = rowb + r;
            if (EPI == 0) {
              v = fast_gelu(v + biasv[nh][n]);
              ((unsigned short*)outp)[(size_t)row * ldo + ocol + col] = f2bf(v);
            } else {
              v += biasv[nh][n];
              ((float*)outp)[(size_t)row * ldo + col] = v;
            }
          }
        }
}

// ==================== small 2-phase GEMM for the LoRA u-projections ====================
// (validated R4 structure: BK=32 triple-buffer ring, counted vmcnt)
// EPI2: acc*2*bw[row][col>>4] -> bf16 out at col offset
template<int BM, int BN, int WM, int WN, int K>
__global__ __launch_bounds__(256) void gemmu_kernel(
    const unsigned short* __restrict__ A, int lda,
    const unsigned short* __restrict__ B, int ldb,
    const float* __restrict__ bw,
    unsigned short* __restrict__ outp, int ldo, int ocol) {
  constexpr int WRM = WM / 16, WRN = WN / 16;
  constexpr int NWN = BN / WN;
  constexpr int NT  = K / 32;
  constexpr int NBUF = 3;
  constexpr int AISS = BM / 64;
  constexpr int BISS = BN / 64;
  constexpr int LOADS = AISS + BISS;
  static_assert((BM / WM) * (BN / WN) == 4, "4 waves");
  __shared__ __align__(16) unsigned short lA[NBUF * BM * 32];
  __shared__ __align__(16) unsigned short lB[NBUF * BN * 32];

  const int tid  = threadIdx.x;
  const int wid  = tid >> 6, lane = tid & 63;
  const int wr   = wid / NWN, wc = wid % NWN;
  const int bm   = blockIdx.x * BM, bn = blockIdx.y * BN;
  const int srow = lane >> 2;
  const int scol = (((lane & 3) ^ ((lane >> 2) & 3)) * 8);
  const int kch  = (((lane >> 4) ^ (lane & 3)) * 8);

  f32x4 acc[WRM][WRN] = {};

  auto stage = [&](int buf, int t) {
    #pragma unroll
    for (int i = 0; i < AISS; i++) {
      int row = i * 64 + wid * 16 + srow;
      __builtin_amdgcn_global_load_lds(
          (const AS1 void*)(A + (size_t)(bm + row) * lda + t * 32 + scol),
          (AS3 void*)(lA + buf * (BM * 32) + i * 2048 + wid * 512), 16, 0, 0);
    }
    #pragma unroll
    for (int i = 0; i < BISS; i++) {
      int row = i * 64 + wid * 16 + srow;
      __builtin_amdgcn_global_load_lds(
          (const AS1 void*)(B + (size_t)(bn + row) * ldb + t * 32 + scol),
          (AS3 void*)(lB + buf * (BN * 32) + i * 2048 + wid * 512), 16, 0, 0);
    }
  };
  auto compute = [&](int buf) {
    const unsigned short* pA = lA + buf * (BM * 32);
    const unsigned short* pB = lB + buf * (BN * 32);
    bf16x8 af[WRM], bfv[WRN];
    #pragma unroll
    for (int m = 0; m < WRM; m++)
      af[m] = *(const bf16x8*)(pA + (wr * WM + m * 16 + (lane & 15)) * 32 + kch);
    #pragma unroll
    for (int n = 0; n < WRN; n++)
      bfv[n] = *(const bf16x8*)(pB + (wc * WN + n * 16 + (lane & 15)) * 32 + kch);
    #pragma unroll
    for (int m = 0; m < WRM; m++)
      #pragma unroll
      for (int n = 0; n < WRN; n++)
        acc[m][n] = __builtin_amdgcn_mfma_f32_16x16x32_bf16(af[m], bfv[n], acc[m][n], 0, 0, 0);
  };

  stage(0, 0); stage(1, 1); stage(2, 2);
  wvm<2 * LOADS>();
  __builtin_amdgcn_s_barrier();

  int bt = 0;
  for (int t = 0; t < NT; ++t) {
    compute(bt);
    __builtin_amdgcn_s_barrier();
    if (t + 1 < NT) {
      if (t + NBUF < NT) stage(bt, t + NBUF);
      int newer = (t + NBUF < NT) ? (NBUF - 1) : (NT - 2 - t);
      if (newer >= 2)      wvm<2 * LOADS>();
      else if (newer == 1) wvm<LOADS>();
      else                 wvm<0>();
      __builtin_amdgcn_s_barrier();
      bt = (bt == NBUF - 1) ? 0 : bt + 1;
    }
  }

  const int r0 = bm + wr * WM;
  const int c0 = bn + wc * WN;
  #pragma unroll
  for (int m = 0; m < WRM; m++)
    #pragma unroll
    for (int n = 0; n < WRN; n++) {
      int col  = c0 + n * 16 + (lane & 15);
      int rowb = r0 + m * 16 + ((lane >> 4) << 2);
      #pragma unroll
      for (int r = 0; r < 4; r++) {
        float v = acc[m][n][r] * 2.0f * bw[(rowb + r) * 4 + (col >> 4)];
        outp[(size_t)(rowb + r) * ldo + ocol + col] = f2bf(v);
      }
    }
}

extern "C" void kernel_launch(void* const* d_in, const int* in_sizes, int n_in,
                              void* d_out, int out_size, void* d_ws, size_t ws_size,
                              hipStream_t stream) {
  const float* x  = (const float*)d_in[0];
  const float* bw = (const float*)d_in[1];
  const float* W1 = (const float*)d_in[2];
  const float* b1 = (const float*)d_in[3];
  const float* W2 = (const float*)d_in[4];
  const float* b2 = (const float*)d_in[5];
  const float* A1 = (const float*)d_in[6];
  const float* B1 = (const float*)d_in[7];
  const float* A2 = (const float*)d_in[8];
  const float* B2 = (const float*)d_in[9];
  float* out = (float*)d_out;

  char* w = (char*)d_ws;
  unsigned short* xaug = (unsigned short*)w;  w += (size_t)NR * K1 * 2;       // 18.9 MB
  unsigned short* haug = (unsigned short*)w;  w += (size_t)NR * K2 * 2;       // 69.2 MB
  unsigned short* W1cT = (unsigned short*)w;  w += (size_t)DHID * K1 * 2;     // 2.36 MB
  unsigned short* W2cT = (unsigned short*)w;  w += (size_t)DOUT * K2 * 2;     // 2.16 MB
  unsigned short* A1T  = (unsigned short*)w;  w += (size_t)64 * DIN * 2;
  unsigned short* A2T  = (unsigned short*)w;  w += (size_t)64 * DHID * 2;

  // --- preprocessing ---
  cvt_x_kernel<<<NR * DIN / 4 / 256, 256, 0, stream>>>(x, xaug);
  tconv_kernel<512, 2048, K1, 0><<<dim3(64, 16), 256, 0, stream>>>(W1, W1cT);
  tconv_kernel<64, 2048, K1, 512><<<dim3(64, 2), 256, 0, stream>>>(B1, W1cT);
  tconv_kernel<2048, 512, K2, 0><<<dim3(16, 64), 256, 0, stream>>>(W2, W2cT);
  tconv_kernel<64, 512, K2, 2048><<<dim3(16, 2), 256, 0, stream>>>(B2, W2cT);
  rearrA_kernel<<<128, 256, 0, stream>>>(A1, A1T, 512);
  rearrA_kernel<<<512, 256, 0, stream>>>(A2, A2T, 2048);

  // --- u1 = 2*bw ⊙ (x @ A1cat)  -> xaug[:, 512:576] ---
  gemmu_kernel<64, 64, 32, 32, 512><<<dim3(NR / 64, 1), 256, 0, stream>>>(
      xaug, K1, A1T, DIN, bw, xaug, K1, 512);
  // --- h = gelu(xaug @ [W1;B1cat] + b1) -> haug[:, 0:2048] ---
  gemm8_kernel<256, K1, 0><<<dim3(NR / 256, DHID / 256), 512, 0, stream>>>(
      xaug, K1, W1cT, K1, b1, haug, K2, 0);
  // --- u2 = 2*bw ⊙ (h @ A2cat) -> haug[:, 2048:2112] ---
  gemmu_kernel<64, 64, 32, 32, 2048><<<dim3(NR / 64, 1), 256, 0, stream>>>(
      haug, K2, A2T, DHID, bw, haug, K2, 2048);
  // --- out = haug @ [W2;B2cat] + b2 (fp32) ---
  gemm8_kernel<128, K2, 1><<<dim3(NR / 128, DOUT / 256), 512, 0, stream>>>(
      haug, K2, W2cT, K2, b2, out, DOUT, 0);
}

// Round 7
// 147.345 us; speedup vs baseline: 1.1591x; 1.0630x over previous
//
#include <hip/hip_runtime.h>
#include <hip/hip_bf16.h>

#define DEV __device__ __forceinline__
#define AS1 __attribute__((address_space(1)))
#define AS3 __attribute__((address_space(3)))

typedef __attribute__((ext_vector_type(8))) short bf16x8;
typedef __attribute__((ext_vector_type(4))) float f32x4;

static constexpr int NR   = 16384;
static constexpr int DIN  = 512;
static constexpr int DHID = 2048;
static constexpr int DOUT = 512;
static constexpr int LR   = 64;          // 4 bands * rank 16
static constexpr int K1   = DIN + LR;    // 576
static constexpr int K2   = DHID + LR;   // 2112

DEV unsigned short f2bf(float f) {
  unsigned u = __float_as_uint(f);
  u += 0x7fffu + ((u >> 16) & 1u);
  return (unsigned short)(u >> 16);
}

// fast GELU: tanh-form, |err vs erf-form| < ~1.5e-3 (well under bf16 quantum of h)
DEV float fast_gelu(float v) {
  float x2 = v * v;
  float a  = -v * __builtin_fmaf(0.10294324f, x2, 2.30220817f);
  float t  = exp2f(a);
  return v * __builtin_amdgcn_rcpf(1.0f + t);
}

template<int N> DEV void wvm() {
  asm volatile("s_waitcnt vmcnt(%0)" :: "i"(N) : "memory");
}

// ---- x fp32 -> bf16 into xaug[:, 0:512] (row stride K1) ----
__global__ __launch_bounds__(256) void cvt_x_kernel(const float* __restrict__ x,
                                                    unsigned short* __restrict__ xaug) {
  int i = blockIdx.x * 256 + threadIdx.x;   // one float4 per thread
  if (i >= NR * DIN / 4) return;
  int e = i * 4;
  int r = e >> 9, c = e & 511;
  float4 v = ((const float4*)x)[i];
  uint2 o;
  o.x = (unsigned)f2bf(v.x) | ((unsigned)f2bf(v.y) << 16);
  o.y = (unsigned)f2bf(v.z) | ((unsigned)f2bf(v.w) << 16);
  *(uint2*)(xaug + (size_t)r * K1 + c) = o;
}

// ---- generic transpose+convert: in fp32 [R][C] -> out bf16 [C][LDO] at col offset CO ----
template<int R, int C, int LDO, int CO>
__global__ __launch_bounds__(256) void tconv_kernel(const float* __restrict__ in,
                                                    unsigned short* __restrict__ out) {
  __shared__ float t[32][33];
  int bc = blockIdx.x * 32, br = blockIdx.y * 32;
  int tx = threadIdx.x & 31, ty = threadIdx.x >> 5;   // ty 0..7
  #pragma unroll
  for (int i = 0; i < 32; i += 8)
    t[ty + i][tx] = in[(size_t)(br + ty + i) * C + bc + tx];
  __syncthreads();
  #pragma unroll
  for (int i = 0; i < 32; i += 8)
    out[(size_t)(bc + ty + i) * LDO + CO + br + tx] = f2bf(t[tx][ty + i]);
}

// ---- LoRA A rearrange: A [4][D][16] fp32 -> AT [64][D] bf16 ----
__global__ __launch_bounds__(256) void rearrA_kernel(const float* __restrict__ A,
                                                     unsigned short* __restrict__ AT, int D) {
  int tid = blockIdx.x * 256 + threadIdx.x;
  if (tid >= 64 * D) return;
  int j = tid / D, i = tid - j * D;
  AT[tid] = f2bf(A[((size_t)(j >> 4) * D + i) * 16 + (j & 15)]);
}

// ========== single-barrier double-buffered MFMA GEMM (T2 swizzle, exact vmcnt) ==========
// Per K-tile: {ldA0,ldB0 | stage tile i+1 (8 loads) | MFMA c00 | ldB1 | MFMA c01 |
//              ldA1 (reg reuse) | MFMA c11,c10 | vmcnt(0) | s_barrier}.
// Sync proof: reads of tile i are MFMA-consumed before the end barrier; stage(i+1)
// goes to the other buffer; stage(i+2) overwrites buf only after all waves passed
// the tile-i end barrier (their tile-i reads long done). One barrier/tile suffices.
// A: [M][lda] bf16 K-contig. B: [BN-col panel][ldb] bf16 K-contig (weight^T).
// EPI: 0 = gelu(acc+bias)->bf16 out ; 1 = acc+bias->fp32 out
template<int BM, int BN, int WAVES, int K, int EPI>
__global__ __launch_bounds__(WAVES * 64, 2) void gemm8_kernel(
    const unsigned short* __restrict__ A, int lda,
    const unsigned short* __restrict__ B, int ldb,
    const float* __restrict__ bias,
    void* __restrict__ outp, int ldo, int ocol) {
  constexpr int THREADS = WAVES * 64;
  constexpr int NT = K / 64;
  constexpr int AL = BM * 4 / THREADS;   // gload_lds/thread per A half (=2)
  constexpr int BL = BN * 4 / THREADS;   // per B half (=2)
  constexpr int HA = (BM / 2) * 64;      // elems per A half-slot
  constexpr int HB = (BN / 2) * 64;
  constexpr int MQ = BM / 64;            // m-frags per cluster per wave
  constexpr int WC = WAVES / 2;          // wave cols
  static_assert(NT >= 2, "K tiles");
  __shared__ __align__(16) unsigned short lA[4 * HA];   // [buf][half]
  __shared__ __align__(16) unsigned short lB[4 * HB];

  const int tid  = threadIdx.x;
  const int w    = tid >> 6, lane = tid & 63;
  const int wr   = w / WC, wc = w % WC;         // 2 x WC wave grid
  const int bm   = blockIdx.x * BM, bn = blockIdx.y * BN;
  const int l15  = lane & 15;
  const int kc0  = ((lane >> 4) ^ (lane & 7)) * 8;        // kk=0 chunk (swizzled)
  const int kc1  = (((lane >> 4) + 4) ^ (lane & 7)) * 8;  // kk=1 chunk

  f32x4 acc[2][2][MQ][2] = {};   // [mh][nh][m][n]
  bf16x8 af[MQ][2];              // A frags for current mh (reused across halves)
  bf16x8 bfv[2][2][2];           // [nh][n][kk]

  auto stageA = [&](int buf, int half, int t) {
    #pragma unroll
    for (int i = 0; i < AL; ++i) {
      int row = w * (AL * 8) + i * 8 + (lane >> 3);
      __builtin_amdgcn_global_load_lds(
          (const AS1 void*)(A + (size_t)(bm + half * (BM / 2) + row) * lda
                              + (size_t)t * 64 + (((lane & 7) ^ (row & 7)) * 8)),
          (AS3 void*)(lA + (buf * 2 + half) * HA + (w * AL + i) * 512),
          16, 0, 0);
    }
  };
  auto stageB = [&](int buf, int half, int t) {
    #pragma unroll
    for (int i = 0; i < BL; ++i) {
      int row = w * (BL * 8) + i * 8 + (lane >> 3);
      __builtin_amdgcn_global_load_lds(
          (const AS1 void*)(B + (size_t)(bn + half * (BN / 2) + row) * ldb
                              + (size_t)t * 64 + (((lane & 7) ^ (row & 7)) * 8)),
          (AS3 void*)(lB + (buf * 2 + half) * HB + (w * BL + i) * 512),
          16, 0, 0);
    }
  };
  auto ldA = [&](int buf, int mh) {
    const unsigned short* sA = lA + (buf * 2 + mh) * HA;
    #pragma unroll
    for (int m = 0; m < MQ; ++m) {
      int ro = (wr * (BM / 4) + m * 16 + l15) * 64;
      af[m][0] = *(const bf16x8*)(sA + ro + kc0);
      af[m][1] = *(const bf16x8*)(sA + ro + kc1);
    }
  };
  auto ldB = [&](int buf, int nh) {
    const unsigned short* sB = lB + (buf * 2 + nh) * HB;
    #pragma unroll
    for (int n = 0; n < 2; ++n) {
      int ro = (wc * 32 + n * 16 + l15) * 64;
      bfv[nh][n][0] = *(const bf16x8*)(sB + ro + kc0);
      bfv[nh][n][1] = *(const bf16x8*)(sB + ro + kc1);
    }
  };

#define MFMA_Q(mh, nh)                                                           \
  __builtin_amdgcn_s_setprio(1);                                                 \
  _Pragma("unroll")                                                              \
  for (int m = 0; m < MQ; ++m)                                                   \
    _Pragma("unroll")                                                            \
    for (int n = 0; n < 2; ++n) {                                                \
      acc[mh][nh][m][n] = __builtin_amdgcn_mfma_f32_16x16x32_bf16(               \
          af[m][0], bfv[nh][n][0], acc[mh][nh][m][n], 0, 0, 0);                  \
      acc[mh][nh][m][n] = __builtin_amdgcn_mfma_f32_16x16x32_bf16(               \
          af[m][1], bfv[nh][n][1], acc[mh][nh][m][n], 0, 0, 0);                  \
    }                                                                            \
  __builtin_amdgcn_s_setprio(0);

  // prologue: stage tile 0 into buf0, exact drain, one barrier
  stageA(0, 0, 0); stageB(0, 0, 0); stageB(0, 1, 0); stageA(0, 1, 0);
  wvm<0>();
  __builtin_amdgcn_s_barrier();

  for (int t = 0; t < NT; ++t) {
    const int buf = t & 1, nb = buf ^ 1;
    const bool more = (t + 1 < NT);
    ldA(buf, 0);               // af <- A-half0 (8|4 reads)
    ldB(buf, 0);               // bfv[0]       (4 reads)
    if (more) {                // stage whole tile t+1 into other buffer (8 loads)
      stageA(nb, 0, t + 1); stageB(nb, 0, t + 1);
      stageB(nb, 1, t + 1); stageA(nb, 1, t + 1);
    }
    MFMA_Q(0, 0);
    ldB(buf, 1);               // bfv[1]       (4 reads, overlaps w/ sibling MFMA)
    MFMA_Q(0, 1);
    ldA(buf, 1);               // af <- A-half1 (reg reuse)
    MFMA_Q(1, 1);
    MFMA_Q(1, 0);
    wvm<0>();                  // exact: only tile t+1's 8 loads outstanding, ~full-tile cover
    __builtin_amdgcn_s_barrier();
  }
#undef MFMA_Q

  // epilogue: C/D layout col=lane&15, row=(lane>>4)*4+reg
  float biasv[2][2];
  #pragma unroll
  for (int nh = 0; nh < 2; ++nh)
    #pragma unroll
    for (int n = 0; n < 2; ++n)
      biasv[nh][n] = bias[bn + nh * (BN / 2) + wc * 32 + n * 16 + l15];

  #pragma unroll
  for (int mh = 0; mh < 2; ++mh)
    #pragma unroll
    for (int nh = 0; nh < 2; ++nh)
      #pragma unroll
      for (int m = 0; m < MQ; ++m)
        #pragma unroll
        for (int n = 0; n < 2; ++n) {
          int col  = bn + nh * (BN / 2) + wc * 32 + n * 16 + l15;
          int rowb = bm + mh * (BM / 2) + wr * (BM / 4) + m * 16 + ((lane >> 4) << 2);
          #pragma unroll
          for (int r = 0; r < 4; ++r) {
            float v = acc[mh][nh][m][n][r];
            int row = rowb + r;
            if (EPI == 0) {
              v = fast_gelu(v + biasv[nh][n]);
              ((unsigned short*)outp)[(size_t)row * ldo + ocol + col] = f2bf(v);
            } else {
              v += biasv[nh][n];
              ((float*)outp)[(size_t)row * ldo + col] = v;
            }
          }
        }
}

// ==================== small 2-phase GEMM for the LoRA u-projections ====================
// (validated R4 structure: BK=32 triple-buffer ring, counted vmcnt)
// EPI2: acc*2*bw[row][col>>4] -> bf16 out at col offset
template<int BM, int BN, int WM, int WN, int K>
__global__ __launch_bounds__(256) void gemmu_kernel(
    const unsigned short* __restrict__ A, int lda,
    const unsigned short* __restrict__ B, int ldb,
    const float* __restrict__ bw,
    unsigned short* __restrict__ outp, int ldo, int ocol) {
  constexpr int WRM = WM / 16, WRN = WN / 16;
  constexpr int NWN = BN / WN;
  constexpr int NT  = K / 32;
  constexpr int NBUF = 3;
  constexpr int AISS = BM / 64;
  constexpr int BISS = BN / 64;
  constexpr int LOADS = AISS + BISS;
  static_assert((BM / WM) * (BN / WN) == 4, "4 waves");
  __shared__ __align__(16) unsigned short lA[NBUF * BM * 32];
  __shared__ __align__(16) unsigned short lB[NBUF * BN * 32];

  const int tid  = threadIdx.x;
  const int wid  = tid >> 6, lane = tid & 63;
  const int wr   = wid / NWN, wc = wid % NWN;
  const int bm   = blockIdx.x * BM, bn = blockIdx.y * BN;
  const int srow = lane >> 2;
  const int scol = (((lane & 3) ^ ((lane >> 2) & 3)) * 8);
  const int kch  = (((lane >> 4) ^ (lane & 3)) * 8);

  f32x4 acc[WRM][WRN] = {};

  auto stage = [&](int buf, int t) {
    #pragma unroll
    for (int i = 0; i < AISS; i++) {
      int row = i * 64 + wid * 16 + srow;
      __builtin_amdgcn_global_load_lds(
          (const AS1 void*)(A + (size_t)(bm + row) * lda + t * 32 + scol),
          (AS3 void*)(lA + buf * (BM * 32) + i * 2048 + wid * 512), 16, 0, 0);
    }
    #pragma unroll
    for (int i = 0; i < BISS; i++) {
      int row = i * 64 + wid * 16 + srow;
      __builtin_amdgcn_global_load_lds(
          (const AS1 void*)(B + (size_t)(bn + row) * ldb + t * 32 + scol),
          (AS3 void*)(lB + buf * (BN * 32) + i * 2048 + wid * 512), 16, 0, 0);
    }
  };
  auto compute = [&](int buf) {
    const unsigned short* pA = lA + buf * (BM * 32);
    const unsigned short* pB = lB + buf * (BN * 32);
    bf16x8 af[WRM], bfv[WRN];
    #pragma unroll
    for (int m = 0; m < WRM; m++)
      af[m] = *(const bf16x8*)(pA + (wr * WM + m * 16 + (lane & 15)) * 32 + kch);
    #pragma unroll
    for (int n = 0; n < WRN; n++)
      bfv[n] = *(const bf16x8*)(pB + (wc * WN + n * 16 + (lane & 15)) * 32 + kch);
    #pragma unroll
    for (int m = 0; m < WRM; m++)
      #pragma unroll
      for (int n = 0; n < WRN; n++)
        acc[m][n] = __builtin_amdgcn_mfma_f32_16x16x32_bf16(af[m], bfv[n], acc[m][n], 0, 0, 0);
  };

  stage(0, 0); stage(1, 1); stage(2, 2);
  wvm<2 * LOADS>();
  __builtin_amdgcn_s_barrier();

  int bt = 0;
  for (int t = 0; t < NT; ++t) {
    compute(bt);
    __builtin_amdgcn_s_barrier();
    if (t + 1 < NT) {
      if (t + NBUF < NT) stage(bt, t + NBUF);
      int newer = (t + NBUF < NT) ? (NBUF - 1) : (NT - 2 - t);
      if (newer >= 2)      wvm<2 * LOADS>();
      else if (newer == 1) wvm<LOADS>();
      else                 wvm<0>();
      __builtin_amdgcn_s_barrier();
      bt = (bt == NBUF - 1) ? 0 : bt + 1;
    }
  }

  const int r0 = bm + wr * WM;
  const int c0 = bn + wc * WN;
  #pragma unroll
  for (int m = 0; m < WRM; m++)
    #pragma unroll
    for (int n = 0; n < WRN; n++) {
      int col  = c0 + n * 16 + (lane & 15);
      int rowb = r0 + m * 16 + ((lane >> 4) << 2);
      #pragma unroll
      for (int r = 0; r < 4; r++) {
        float v = acc[m][n][r] * 2.0f * bw[(rowb + r) * 4 + (col >> 4)];
        outp[(size_t)(rowb + r) * ldo + ocol + col] = f2bf(v);
      }
    }
}

extern "C" void kernel_launch(void* const* d_in, const int* in_sizes, int n_in,
                              void* d_out, int out_size, void* d_ws, size_t ws_size,
                              hipStream_t stream) {
  const float* x  = (const float*)d_in[0];
  const float* bw = (const float*)d_in[1];
  const float* W1 = (const float*)d_in[2];
  const float* b1 = (const float*)d_in[3];
  const float* W2 = (const float*)d_in[4];
  const float* b2 = (const float*)d_in[5];
  const float* A1 = (const float*)d_in[6];
  const float* B1 = (const float*)d_in[7];
  const float* A2 = (const float*)d_in[8];
  const float* B2 = (const float*)d_in[9];
  float* out = (float*)d_out;

  char* w = (char*)d_ws;
  unsigned short* xaug = (unsigned short*)w;  w += (size_t)NR * K1 * 2;       // 18.9 MB
  unsigned short* haug = (unsigned short*)w;  w += (size_t)NR * K2 * 2;       // 69.2 MB
  unsigned short* W1cT = (unsigned short*)w;  w += (size_t)DHID * K1 * 2;     // 2.36 MB
  unsigned short* W2cT = (unsigned short*)w;  w += (size_t)DOUT * K2 * 2;     // 2.16 MB
  unsigned short* A1T  = (unsigned short*)w;  w += (size_t)64 * DIN * 2;
  unsigned short* A2T  = (unsigned short*)w;  w += (size_t)64 * DHID * 2;

  // --- preprocessing ---
  cvt_x_kernel<<<NR * DIN / 4 / 256, 256, 0, stream>>>(x, xaug);
  tconv_kernel<512, 2048, K1, 0><<<dim3(64, 16), 256, 0, stream>>>(W1, W1cT);
  tconv_kernel<64, 2048, K1, 512><<<dim3(64, 2), 256, 0, stream>>>(B1, W1cT);
  tconv_kernel<2048, 512, K2, 0><<<dim3(16, 64), 256, 0, stream>>>(W2, W2cT);
  tconv_kernel<64, 512, K2, 2048><<<dim3(16, 2), 256, 0, stream>>>(B2, W2cT);
  rearrA_kernel<<<128, 256, 0, stream>>>(A1, A1T, 512);
  rearrA_kernel<<<512, 256, 0, stream>>>(A2, A2T, 2048);

  // --- u1 = 2*bw ⊙ (x @ A1cat)  -> xaug[:, 512:576] ---
  gemmu_kernel<64, 64, 32, 32, 512><<<dim3(NR / 64, 1), 256, 0, stream>>>(
      xaug, K1, A1T, DIN, bw, xaug, K1, 512);
  // --- h = gelu(xaug @ [W1;B1cat] + b1) -> haug[:, 0:2048]  (256x256, 8 waves) ---
  gemm8_kernel<256, 256, 8, K1, 0><<<dim3(NR / 256, DHID / 256), 512, 0, stream>>>(
      xaug, K1, W1cT, K1, b1, haug, K2, 0);
  // --- u2 = 2*bw ⊙ (h @ A2cat) -> haug[:, 2048:2112] ---
  gemmu_kernel<64, 64, 32, 32, 2048><<<dim3(NR / 64, 1), 256, 0, stream>>>(
      haug, K2, A2T, DHID, bw, haug, K2, 2048);
  // --- out = haug @ [W2;B2cat] + b2 (fp32)  (128x128, 4 waves, 2 blocks/CU) ---
  gemm8_kernel<128, 128, 4, K2, 1><<<dim3(NR / 128, DOUT / 128), 256, 0, stream>>>(
      haug, K2, W2cT, K2, b2, out, DOUT, 0);
}